// Round 2
// baseline (841.124 us; speedup 1.0000x reference)
//
#include <hip/hip_runtime.h>
#include <math.h>

#define HH 1024
#define AA 180
#define BB 16
#define NCOL (BB*AA)          // 2880 (b,angle) columns
#define RSP 1028              // pair-row stride (float2 entries)
#define GUARD 48              // fallback path: zero guard floats each side
#define RS 1120               // fallback row stride
#define PI_D 3.14159265358979323846

#define GANG 45               // angles staged per group (180 = 4*45)
#define WIN 48                // window entries (float2) per angle

// ws float-offsets
#define OFF_CG   0            // 512 filter coeffs
#define OFF_CST  512          // float4[180]: (512c, 512s, D8=-8*DEL*512*s, 0)
#define OFF_CST2 1232         // float2[180]: (c,s) fallback table
#define OFF_DATA 1600         // pair rows (float2[NCOL*RSP]) or fallback xaf

__device__ __forceinline__ float fractf_(float x) {
#if __has_builtin(__builtin_amdgcn_fractf)
    return __builtin_amdgcn_fractf(x);   // v_fract_f32
#else
    return x - floorf(x);
#endif
}

// readlane: pulls lane g's value to an SGPR WITHOUT touching the LDS crossbar
// (__shfl compiles to ds_bpermute, which consumes LDS issue slots — the
// saturated pipe). g may be a uniform runtime value (SGPR lane select).
__device__ __forceinline__ float rdlane_f(float v, int g) {
    return __int_as_float(__builtin_amdgcn_readlane(__float_as_int(v), g));
}

// ---------------- tables ----------------
__global__ __launch_bounds__(512) void k_tables(float* __restrict__ ws) {
    int t = threadIdx.x;
    if (t < 512) {
        double d = 2.0 * t + 1.0;
        ws[OFF_CG + t] = (float)(-2.0 / (PI_D * PI_D * d * d));
    }
    if (t < AA) {
        float thf = (float)t * 0.017453292519943295f;  // fp32(pi/180)
        double th = (double)thf;
        double c = cos(th), s = sin(th);
        float4* cst4 = (float4*)(ws + OFF_CST);
        // D8 = d(iy)/d(k) for y-step of 8 pixels: -8*DEL*512*s = -(8192/1023)*s
        cst4[t] = make_float4((float)(512.0 * c), (float)(512.0 * s),
                              (float)(-(8192.0 / 1023.0) * s), 0.f);
        float2* cst2 = (float2*)(ws + OFF_CST2);
        cst2[t] = make_float2((float)(512.0 * c), (float)(512.0 * s));
    }
}

// ---------------- shared conv core (fused angle-interp + ramp filter) ----------------
__device__ __forceinline__ void filter_core(const float* __restrict__ x,
                                            const float* __restrict__ cg,
                                            float* xsp, int t, int col,
                                            float acc[16]) {
    int b = col / AA, a = col - b * AA;

    float4* z4 = (float4*)xsp;
    #pragma unroll
    for (int i = t; i < 816; i += 64) z4[i] = make_float4(0.f, 0.f, 0.f, 0.f);
    __syncthreads();

    float ixf = (float)a * (float)(180.0/179.0) - 0.5f;
    float fl = floorf(ixf);
    int i0 = (int)fl;
    float fx = ixf - fl;
    float w0 = (i0 >= 0)      ? (1.0f - fx) : 0.0f;
    float w1 = (i0 + 1 < AA)  ? fx          : 0.0f;
    int c0 = max(i0, 0);
    int c1 = min(i0 + 1, AA - 1);
    const float* xb = x + (size_t)b * HH * AA;
    for (int i = t; i < HH; i += 64) {
        float v = w0 * xb[i * AA + c0] + w1 * xb[i * AA + c1];
        int q = 1024 + i;
        xsp[q + (q >> 4)] = v;         // lane stride 17 -> conflict-free
    }
    __syncthreads();

    int pp = 17 * t;
    float Lw[16], Rw[16];
    #pragma unroll
    for (int m = 0; m < 16; ++m) {
        int f = 1024 + m;
        acc[m] = 0.5f * xsp[pp + f + (f >> 4)];
    }
    #pragma unroll
    for (int m = 0; m < 16; ++m) {
        int f = 1 + m;
        Lw[(m + 1) & 15] = xsp[pp + f + (f >> 4)];
        int g = 2047 + m;
        Rw[(m - 1) & 15] = xsp[pp + g + (g >> 4)];
    }

    for (int it0 = 0; it0 < 512; it0 += 8) {
        #pragma unroll
        for (int u = 0; u < 8; ++u) {
            int it = it0 + u;
            float cv = cg[511 - it];
            #pragma unroll
            for (int m = 0; m < 16; ++m) {
                acc[m] = fmaf(cv, Lw[(m + 2*u + 1) & 15] + Rw[(m - 2*u - 1) & 15], acc[m]);
            }
            int fL  = 2*it + 17;
            Lw[(2*u + 1) & 15] = xsp[pp + fL  + (fL  >> 4)];
            int fL2 = 2*it + 18;
            Lw[(2*u + 2) & 15] = xsp[pp + fL2 + (fL2 >> 4)];
            int fR  = 2045 - 2*it;
            Rw[(13 - 2*u) & 15] = xsp[pp + fR  + (fR  >> 4)];
            int fR2 = 2046 - 2*it;
            Rw[(14 - 2*u) & 15] = xsp[pp + fR2 + (fR2 >> 4)];
        }
    }
}

// ---------------- pair-output filter (SLOPE layout) ----------------
// pair[s] = (y[s-2], y[s-1]-y[s-2]) * SC, zero outside; valid s in [0,1026].
__global__ __launch_bounds__(64) void k_filter_pair(const float* __restrict__ x,
                                                    const float* __restrict__ cg,
                                                    float2* __restrict__ pair) {
    __shared__ float xsp[3264];
    int t = threadIdx.x;
    int col = blockIdx.x;
    float acc[16];
    filter_core(x, cg, xsp, t, col, acc);

    const float SC = (float)(PI_D / 360.0);
    float yv[16];
    #pragma unroll
    for (int m = 0; m < 16; ++m) yv[m] = acc[m] * SC;
    float ynext = __shfl_down(yv[0], 1);
    if (t == 63) ynext = 0.f;

    float2* rowp = pair + (size_t)col * RSP;
    int s0 = 16 * t + 2;
    #pragma unroll
    for (int m = 0; m < 15; ++m) rowp[s0 + m] = make_float2(yv[m], yv[m + 1] - yv[m]);
    rowp[s0 + 15] = make_float2(yv[15], ynext - yv[15]);
    if (t == 0) {
        rowp[0] = make_float2(0.f, 0.f);
        rowp[1] = make_float2(0.f, yv[0]);     // (v=0, dv=y0-0)
    }
    if (t == 63) rowp[1026] = make_float2(0.f, 0.f);
}

// ---------------- LDS-staged backprojection (R2: DS off-load) ----------------
// LDS is the saturated pipe (R1: 4 b64 + 1 b128 = ~32 cyc/wave-angle ~= 495us
// floor ~= 482us measured). This round:
//  (1) per-angle constants via ONE lane-spread ds_read_b128 per group per wave,
//      then v_readlane per angle (VALU, not LDS) -> const b128 removed.
//  (2) pixel-3 gather moved to GLOBAL (pair slab is L2-resident; VMEM idle).
//      j3_glob = j3_win + (int)(513.5f - bf) is exact -> bit-identical data/f.
// New DS/wave-angle: 3 b64 ~= 18 cyc -> ~280us LDS floor.
__global__ __launch_bounds__(256, 4) void k_bproj_lds(const float* __restrict__ ws,
                                                      const float2* __restrict__ pair,
                                                      float* __restrict__ out) {
    __shared__ float4 winbuf[GANG * (WIN/2)];   // 17280 B, 16B-aligned
    __shared__ float4 angf4[GANG];              // (512c, 512s, D8, bf)
    __shared__ int    baseL[GANG];

    const float4* cst = (const float4*)(ws + OFF_CST);
    int t = threadIdx.x;
    int n = blockIdx.x;
    // XCD-batch swizzle: blocks ≡ i (mod 8) handle batches {i, i+8} -> per-XCD
    // pair working set ~3 MB -> L2-resident.
    int b    = (n & 7) + 8 * ((n >> 3) & 1);
    int tile = n >> 4;                  // [0,1024)
    int bx = tile & 31;                 // x-tile (32 px)
    int by = tile >> 5;                 // y-tile (32 px)
    int tx = t & 31;
    int ty = t >> 5;                    // [0,8)
    int xg = bx * 32 + tx;
    int y0 = by * 32;
    int yg = y0 + ty;                   // pixel k at yg + 8k

    const float DEL = (float)(2.0 / 1023.0);
    // bit-exact jnp.linspace replication (mul then add, no contraction)
    float ux  = __fadd_rn(__fmul_rn((float)xg, DEL), -1.0f);
    float uy  = __fadd_rn(__fmul_rn((float)yg, DEL), -1.0f);
    float nuy = -uy;

    // tile-uniform corner coords
    float cxl = __fadd_rn(__fmul_rn((float)(bx*32),      DEL), -1.0f);
    float cxh = __fadd_rn(__fmul_rn((float)(bx*32 + 31), DEL), -1.0f);
    float cyl = __fadd_rn(__fmul_rn((float)(y0),         DEL), -1.0f);
    float cyh = __fadd_rn(__fmul_rn((float)(y0 + 31),    DEL), -1.0f);

    float minax = (cxl <= 0.f && cxh >= 0.f) ? 0.f : fminf(fabsf(cxl), fabsf(cxh));
    float minay = (cyl <= 0.f && cyh >= 0.f) ? 0.f : fminf(fabsf(cyl), fabsf(cyh));
    float rmin2 = minax * minax + minay * minay;
    float maxax = fmaxf(fabsf(cxl), fabsf(cxh));
    float maxay = fmaxf(fabsf(cyl), fabsf(cyh));
    float rmax2 = maxax * maxax + maxay * maxay;

    size_t o0 = ((size_t)b << 20) + ((size_t)yg << 10) + (size_t)xg;
    float* p0 = out + o0;

    if (rmin2 > 1.000001f) {            // tile fully outside: zeros, no barriers hit
        p0[0] = 0.f; p0[8 << 10] = 0.f; p0[16 << 10] = 0.f; p0[24 << 10] = 0.f;
        return;
    }

    bool interior = (rmax2 <= 0.9999f);
    const float2* slab = pair + (size_t)b * (AA * RSP);
    const float2* win = (const float2*)winbuf;
    float a0 = 0.f, a1 = 0.f, a2 = 0.f, a3 = 0.f;
    float nyl = -cyl, nyh = -cyh;

    for (int g0 = 0; g0 < AA; g0 += GANG) {
        // --- per-angle window bases + constants (tile-uniform) ---
        if (t < GANG) {
            float4 cs = cst[g0 + t];    // vector load (t varies)
            float mpx = fminf(cxl * cs.x, cxh * cs.x);
            float mpy = fminf(nyl * cs.y, nyh * cs.y);
            float minP = mpx + mpy + 513.5f;
            int base = (int)floorf(minP) - 1;
            base = min(max(base, 0), 1027 - WIN);
            base &= ~1;                 // 16B-align window for float4 staging
            baseL[t] = base;
            angf4[t] = make_float4(cs.x, cs.y, cs.z, 513.5f - (float)base);
        }
        __syncthreads();

        // lane-spread constants: lane g holds angle g's float4 (one b128/wave/group)
        int li = t & 63;
        float4 cl = angf4[li < GANG ? li : 0];

        // --- coalesced staging: 45 angles x 24 float4 (48 float2) ---
        for (int idx = t; idx < GANG * (WIN/2); idx += 256) {
            int al = idx / (WIN/2);
            int w  = idx - (WIN/2) * al;
            const float4* rp4 = (const float4*)(slab + (size_t)(g0 + al) * RSP + baseL[al]);
            winbuf[idx] = rp4[w];
        }
        __syncthreads();

        const float2* slabg = slab + (size_t)g0 * RSP;   // group's first row

        // --- compute 45 angles: 3 gathers from LDS + 1 from L2 (VMEM pipe) ---
        if (interior) {
            #pragma unroll 5
            for (int g = 0; g < GANG; ++g) {
                float cx = rdlane_f(cl.x, g);
                float cy = rdlane_f(cl.y, g);
                float dz = rdlane_f(cl.z, g);
                float bf = rdlane_f(cl.w, g);
                int   ib = (int)(513.5f - bf);  // exact: window base integer
                float P0 = fmaf(ux, cx, fmaf(nuy, cy, bf));
                float P1 = P0 + dz;
                float P2 = fmaf(2.0f, dz, P0);
                float P3 = P2 + dz;
                int j0 = (int)P0, j1 = (int)P1, j2 = (int)P2, j3 = (int)P3;
                const float2* wg = win + g * WIN;
                float2 d0 = wg[j0];
                float2 d1 = wg[j1];
                float2 d2 = wg[j2];
                float2 d3 = slabg[(size_t)g * RSP + (j3 + ib)];  // L2 gather, same bits
                float f0 = fractf_(P0), f1 = fractf_(P1), f2v = fractf_(P2), f3 = fractf_(P3);
                a0 = fmaf(f0, d0.y, a0 + d0.x);
                a1 = fmaf(f1, d1.y, a1 + d1.x);
                a2 = fmaf(f2v, d2.y, a2 + d2.x);
                a3 = fmaf(f3, d3.y, a3 + d3.x);
            }
        } else {
            #pragma unroll 5
            for (int g = 0; g < GANG; ++g) {
                float cx = rdlane_f(cl.x, g);
                float cy = rdlane_f(cl.y, g);
                float dz = rdlane_f(cl.z, g);
                float bf = rdlane_f(cl.w, g);
                int   ib = (int)(513.5f - bf);
                float P0 = fmaf(ux, cx, fmaf(nuy, cy, bf));
                float P1 = P0 + dz;
                float P2 = fmaf(2.0f, dz, P0);
                float P3 = P2 + dz;
                int j0 = (int)P0, j1 = (int)P1, j2 = (int)P2, j3 = (int)P3;
                j0 = min(max(j0, 0), WIN - 1); j1 = min(max(j1, 0), WIN - 1);
                j2 = min(max(j2, 0), WIN - 1); j3 = min(max(j3, 0), WIN - 1);
                const float2* wg = win + g * WIN;
                float2 d0 = wg[j0];
                float2 d1 = wg[j1];
                float2 d2 = wg[j2];
                // clamped j3 + ib stays in [base, base+47] ⊆ [0,1025]: in-bounds
                float2 d3 = slabg[(size_t)g * RSP + (j3 + ib)];
                float f0 = fractf_(P0), f1 = fractf_(P1), f2v = fractf_(P2), f3 = fractf_(P3);
                a0 = fmaf(f0, d0.y, a0 + d0.x);
                a1 = fmaf(f1, d1.y, a1 + d1.x);
                a2 = fmaf(f2v, d2.y, a2 + d2.x);
                a3 = fmaf(f3, d3.y, a3 + d3.x);
            }
        }
        __syncthreads();   // protect baseL/angf4/win before next group
    }

    if (interior) {
        p0[0] = a0; p0[8 << 10] = a1; p0[16 << 10] = a2; p0[24 << 10] = a3;
    } else {
        // bit-exact circle mask per pixel (in-circle px had exact j/fract; out px masked)
        float uy1 = __fadd_rn(__fmul_rn((float)(yg + 8),  DEL), -1.0f);
        float uy2 = __fadd_rn(__fmul_rn((float)(yg + 16), DEL), -1.0f);
        float uy3 = __fadd_rn(__fmul_rn((float)(yg + 24), DEL), -1.0f);
        float xx = __fmul_rn(ux, ux);
        float r20 = __fadd_rn(xx, __fmul_rn(uy,  uy));
        float r21 = __fadd_rn(xx, __fmul_rn(uy1, uy1));
        float r22 = __fadd_rn(xx, __fmul_rn(uy2, uy2));
        float r23 = __fadd_rn(xx, __fmul_rn(uy3, uy3));
        p0[0]        = (r20 <= 1.0f) ? a0 : 0.f;
        p0[8 << 10]  = (r21 <= 1.0f) ? a1 : 0.f;
        p0[16 << 10] = (r22 <= 1.0f) ? a2 : 0.f;
        p0[24 << 10] = (r23 <= 1.0f) ? a3 : 0.f;
    }
}

// ================= fallback path (R3, proven) — used if ws too small ==========
__global__ __launch_bounds__(64) void k_filter_sc(const float* __restrict__ x,
                                                  const float* __restrict__ cg,
                                                  float* __restrict__ xaf) {
    __shared__ float xsp[3264];
    int t = threadIdx.x;
    int col = blockIdx.x;
    float acc[16];
    filter_core(x, cg, xsp, t, col, acc);

    const float SC = (float)(PI_D / 360.0);
    float* rb = xaf + (size_t)col * RS;
    if (t < 12)            ((float4*)rb)[t]              = make_float4(0.f,0.f,0.f,0.f);
    else if (t < 24)       ((float4*)rb)[268 + (t - 12)] = make_float4(0.f,0.f,0.f,0.f);
    float4* o4 = (float4*)(rb + GUARD + 16 * t);
    #pragma unroll
    for (int m4 = 0; m4 < 4; ++m4)
        o4[m4] = make_float4(acc[4*m4]*SC, acc[4*m4+1]*SC, acc[4*m4+2]*SC, acc[4*m4+3]*SC);
}

__global__ __launch_bounds__(256, 4) void k_bproj_sc(const float* __restrict__ ws,
                                                     const float* __restrict__ xaf,
                                                     float* __restrict__ out) {
    const float2* cst2 = (const float2*)(ws + OFF_CST2);
    int t = threadIdx.x;
    int tx = t & 15, ty = t >> 4;
    int bx = blockIdx.x, by = blockIdx.y, b = blockIdx.z;
    int xg = bx * 16 + tx, yg = by * 16 + ty;
    const float DEL = (float)(2.0 / 1023.0);
    float ux = __fadd_rn(__fmul_rn((float)xg, DEL), -1.0f);
    float uy = __fadd_rn(__fmul_rn((float)yg, DEL), -1.0f);

    float cx0 = __fadd_rn(__fmul_rn((float)(bx*16),      DEL), -1.0f);
    float cx1 = __fadd_rn(__fmul_rn((float)(bx*16 + 15), DEL), -1.0f);
    float cy0 = __fadd_rn(__fmul_rn((float)(by*16),      DEL), -1.0f);
    float cy1 = __fadd_rn(__fmul_rn((float)(by*16 + 15), DEL), -1.0f);
    float minax = (cx0 <= 0.f && cx1 >= 0.f) ? 0.f : fminf(fabsf(cx0), fabsf(cx1));
    float minay = (cy0 <= 0.f && cy1 >= 0.f) ? 0.f : fminf(fabsf(cy0), fabsf(cy1));
    float rmin2 = minax * minax + minay * minay;

    size_t oidx = ((size_t)b << 20) + ((size_t)yg << 10) + (size_t)xg;
    if (rmin2 > 1.000001f) { out[oidx] = 0.f; return; }

    const float* row = xaf + (size_t)b * (AA * RS);
    const float BIAS = 511.5f + (float)GUARD;
    float nuy = -uy;
    float acc = 0.f;

    #pragma unroll 4
    for (int a = 0; a < AA; ++a) {
        float2 cs = cst2[a];
        float iy = fmaf(ux, cs.x, fmaf(nuy, cs.y, BIAS));
        int j = (int)iy;
        float fy = fractf_(iy);
        float v0 = row[j];
        float v1 = row[j + 1];
        acc = fmaf(fy, v1 - v0, acc + v0);
        row += RS;
    }

    float r2 = __fadd_rn(__fmul_rn(ux, ux), __fmul_rn(uy, uy));
    out[oidx] = (r2 <= 1.0f) ? acc : 0.f;
}

extern "C" void kernel_launch(void* const* d_in, const int* in_sizes, int n_in,
                              void* d_out, int out_size, void* d_ws, size_t ws_size,
                              hipStream_t stream) {
    const float* x = (const float*)d_in[0];
    float* out = (float*)d_out;
    float* ws = (float*)d_ws;
    float* cg  = ws + OFF_CG;

    hipLaunchKernelGGL(k_tables, dim3(1), dim3(512), 0, stream, ws);

    size_t need_pair = (size_t)OFF_DATA * 4 + (size_t)NCOL * RSP * sizeof(float2);
    if (ws_size >= need_pair) {
        float2* pair = (float2*)(ws + OFF_DATA);
        hipLaunchKernelGGL(k_filter_pair, dim3(NCOL), dim3(64), 0, stream, x, cg, pair);
        hipLaunchKernelGGL(k_bproj_lds, dim3(16384), dim3(256), 0, stream, ws, pair, out);
    } else {
        float* xaf = ws + OFF_DATA;
        hipLaunchKernelGGL(k_filter_sc, dim3(NCOL), dim3(64), 0, stream, x, cg, xaf);
        hipLaunchKernelGGL(k_bproj_sc, dim3(64, 64, BB), dim3(256), 0, stream, ws, xaf, out);
    }
}

// Round 3
// 760.606 us; speedup vs baseline: 1.1059x; 1.1059x over previous
//
#include <hip/hip_runtime.h>
#include <math.h>

#define HH 1024
#define AA 180
#define BB 16
#define NCOL (BB*AA)          // 2880 (b,angle) columns
#define RSP 1028              // pair-row stride (float2 entries)
#define GUARD 48              // fallback path: zero guard floats each side
#define RS 1120               // fallback row stride
#define PI_D 3.14159265358979323846

#define GANG 45               // angles staged per group (180 = 4*45)
#define WIN 48                // window entries (float2) per angle

// ws float-offsets
#define OFF_CG   0            // 512 filter coeffs
#define OFF_CST  512          // float4[180]: (512c, 512s, D8=-8*DEL*512*s, 0)
#define OFF_CST2 1232         // float2[180]: (c,s) fallback table
#define OFF_DATA 1600         // pair rows (float2[NCOL*RSP]) or fallback xaf

__device__ __forceinline__ float fractf_(float x) {
#if __has_builtin(__builtin_amdgcn_fractf)
    return __builtin_amdgcn_fractf(x);   // v_fract_f32
#else
    return x - floorf(x);
#endif
}

// readlane: pulls lane g's value to an SGPR WITHOUT touching the LDS crossbar.
// (R2 lesson: this part was fine; the global d3 gather was the regression.)
__device__ __forceinline__ float rdlane_f(float v, int g) {
    return __int_as_float(__builtin_amdgcn_readlane(__float_as_int(v), g));
}

// ---------------- tables ----------------
__global__ __launch_bounds__(512) void k_tables(float* __restrict__ ws) {
    int t = threadIdx.x;
    if (t < 512) {
        double d = 2.0 * t + 1.0;
        ws[OFF_CG + t] = (float)(-2.0 / (PI_D * PI_D * d * d));
    }
    if (t < AA) {
        float thf = (float)t * 0.017453292519943295f;  // fp32(pi/180)
        double th = (double)thf;
        double c = cos(th), s = sin(th);
        float4* cst4 = (float4*)(ws + OFF_CST);
        // D8 = d(iy)/d(k) for y-step of 8 pixels: -8*DEL*512*s = -(8192/1023)*s
        cst4[t] = make_float4((float)(512.0 * c), (float)(512.0 * s),
                              (float)(-(8192.0 / 1023.0) * s), 0.f);
        float2* cst2 = (float2*)(ws + OFF_CST2);
        cst2[t] = make_float2((float)(512.0 * c), (float)(512.0 * s));
    }
}

// ---------------- shared conv core (fused angle-interp + ramp filter) ----------------
__device__ __forceinline__ void filter_core(const float* __restrict__ x,
                                            const float* __restrict__ cg,
                                            float* xsp, int t, int col,
                                            float acc[16]) {
    int b = col / AA, a = col - b * AA;

    float4* z4 = (float4*)xsp;
    #pragma unroll
    for (int i = t; i < 816; i += 64) z4[i] = make_float4(0.f, 0.f, 0.f, 0.f);
    __syncthreads();

    float ixf = (float)a * (float)(180.0/179.0) - 0.5f;
    float fl = floorf(ixf);
    int i0 = (int)fl;
    float fx = ixf - fl;
    float w0 = (i0 >= 0)      ? (1.0f - fx) : 0.0f;
    float w1 = (i0 + 1 < AA)  ? fx          : 0.0f;
    int c0 = max(i0, 0);
    int c1 = min(i0 + 1, AA - 1);
    const float* xb = x + (size_t)b * HH * AA;
    for (int i = t; i < HH; i += 64) {
        float v = w0 * xb[i * AA + c0] + w1 * xb[i * AA + c1];
        int q = 1024 + i;
        xsp[q + (q >> 4)] = v;         // lane stride 17 -> conflict-free
    }
    __syncthreads();

    int pp = 17 * t;
    float Lw[16], Rw[16];
    #pragma unroll
    for (int m = 0; m < 16; ++m) {
        int f = 1024 + m;
        acc[m] = 0.5f * xsp[pp + f + (f >> 4)];
    }
    #pragma unroll
    for (int m = 0; m < 16; ++m) {
        int f = 1 + m;
        Lw[(m + 1) & 15] = xsp[pp + f + (f >> 4)];
        int g = 2047 + m;
        Rw[(m - 1) & 15] = xsp[pp + g + (g >> 4)];
    }

    for (int it0 = 0; it0 < 512; it0 += 8) {
        #pragma unroll
        for (int u = 0; u < 8; ++u) {
            int it = it0 + u;
            float cv = cg[511 - it];
            #pragma unroll
            for (int m = 0; m < 16; ++m) {
                acc[m] = fmaf(cv, Lw[(m + 2*u + 1) & 15] + Rw[(m - 2*u - 1) & 15], acc[m]);
            }
            int fL  = 2*it + 17;
            Lw[(2*u + 1) & 15] = xsp[pp + fL  + (fL  >> 4)];
            int fL2 = 2*it + 18;
            Lw[(2*u + 2) & 15] = xsp[pp + fL2 + (fL2 >> 4)];
            int fR  = 2045 - 2*it;
            Rw[(13 - 2*u) & 15] = xsp[pp + fR  + (fR  >> 4)];
            int fR2 = 2046 - 2*it;
            Rw[(14 - 2*u) & 15] = xsp[pp + fR2 + (fR2 >> 4)];
        }
    }
}

// ---------------- pair-output filter (SLOPE layout) ----------------
// pair[s] = (y[s-2], y[s-1]-y[s-2]) * SC, zero outside; valid s in [0,1026].
__global__ __launch_bounds__(64) void k_filter_pair(const float* __restrict__ x,
                                                    const float* __restrict__ cg,
                                                    float2* __restrict__ pair) {
    __shared__ float xsp[3264];
    int t = threadIdx.x;
    int col = blockIdx.x;
    float acc[16];
    filter_core(x, cg, xsp, t, col, acc);

    const float SC = (float)(PI_D / 360.0);
    float yv[16];
    #pragma unroll
    for (int m = 0; m < 16; ++m) yv[m] = acc[m] * SC;
    float ynext = __shfl_down(yv[0], 1);
    if (t == 63) ynext = 0.f;

    float2* rowp = pair + (size_t)col * RSP;
    int s0 = 16 * t + 2;
    #pragma unroll
    for (int m = 0; m < 15; ++m) rowp[s0 + m] = make_float2(yv[m], yv[m + 1] - yv[m]);
    rowp[s0 + 15] = make_float2(yv[15], ynext - yv[15]);
    if (t == 0) {
        rowp[0] = make_float2(0.f, 0.f);
        rowp[1] = make_float2(0.f, yv[0]);     // (v=0, dv=y0-0)
    }
    if (t == 63) rowp[1026] = make_float2(0.f, 0.f);
}

// ---------------- LDS-staged backprojection (R3) ----------------
// R2 post-mortem: all 4 gathers STAY in LDS (scattered b64 ~6 cyc/instr is the
// cheap path; a 64-lane scattered global load costs as much in TA processing
// PLUS unhidden L2 latency -> 482->749us regression). This round keeps only the
// proven parts of R2's idea:
//  (1) per-angle constants come from the tiny global cst table (L1-resident)
//      as one lane-spread float4 per wave per group + v_readlane per angle
//      -> the per-angle ds_read_b128 broadcast is GONE from the LDS pipe.
//  (2) window bases for ALL 180 angles computed once up-front into baseL[AA]
//      -> angf4 LDS array, its writes, and one barrier per group deleted.
// DS/wave-angle: 4 scattered b64 ~= 24 cyc -> ~394us LDS floor.
__global__ __launch_bounds__(256, 4) void k_bproj_lds(const float* __restrict__ ws,
                                                      const float2* __restrict__ pair,
                                                      float* __restrict__ out) {
    __shared__ float4 winbuf[GANG * (WIN/2)];   // 17280 B, 16B-aligned
    __shared__ int    baseL[AA];                // all 180 window bases

    const float4* cst = (const float4*)(ws + OFF_CST);
    int t = threadIdx.x;
    int n = blockIdx.x;
    // XCD-batch swizzle: blocks ≡ i (mod 8) handle batches {i, i+8} -> per-XCD
    // pair working set ~3 MB -> L2-resident.
    int b    = (n & 7) + 8 * ((n >> 3) & 1);
    int tile = n >> 4;                  // [0,1024)
    int bx = tile & 31;                 // x-tile (32 px)
    int by = tile >> 5;                 // y-tile (32 px)
    int tx = t & 31;
    int ty = t >> 5;                    // [0,8)
    int xg = bx * 32 + tx;
    int y0 = by * 32;
    int yg = y0 + ty;                   // pixel k at yg + 8k

    const float DEL = (float)(2.0 / 1023.0);
    // bit-exact jnp.linspace replication (mul then add, no contraction)
    float ux  = __fadd_rn(__fmul_rn((float)xg, DEL), -1.0f);
    float uy  = __fadd_rn(__fmul_rn((float)yg, DEL), -1.0f);
    float nuy = -uy;

    // tile-uniform corner coords
    float cxl = __fadd_rn(__fmul_rn((float)(bx*32),      DEL), -1.0f);
    float cxh = __fadd_rn(__fmul_rn((float)(bx*32 + 31), DEL), -1.0f);
    float cyl = __fadd_rn(__fmul_rn((float)(y0),         DEL), -1.0f);
    float cyh = __fadd_rn(__fmul_rn((float)(y0 + 31),    DEL), -1.0f);

    float minax = (cxl <= 0.f && cxh >= 0.f) ? 0.f : fminf(fabsf(cxl), fabsf(cxh));
    float minay = (cyl <= 0.f && cyh >= 0.f) ? 0.f : fminf(fabsf(cyl), fabsf(cyh));
    float rmin2 = minax * minax + minay * minay;
    float maxax = fmaxf(fabsf(cxl), fabsf(cxh));
    float maxay = fmaxf(fabsf(cyl), fabsf(cyh));
    float rmax2 = maxax * maxax + maxay * maxay;

    size_t o0 = ((size_t)b << 20) + ((size_t)yg << 10) + (size_t)xg;
    float* p0 = out + o0;

    if (rmin2 > 1.000001f) {            // tile fully outside: zeros, no barriers hit
        p0[0] = 0.f; p0[8 << 10] = 0.f; p0[16 << 10] = 0.f; p0[24 << 10] = 0.f;
        return;                          // block-uniform: no divergent-barrier hazard
    }

    bool interior = (rmax2 <= 0.9999f);
    const float2* slab = pair + (size_t)b * (AA * RSP);
    const float2* win = (const float2*)winbuf;
    float a0 = 0.f, a1 = 0.f, a2 = 0.f, a3 = 0.f;
    float nyl = -cyl, nyh = -cyh;

    // --- all-angle window bases, once (same ops/bits as per-group version) ---
    if (t < AA) {
        float4 cs = cst[t];
        float mpx = fminf(cxl * cs.x, cxh * cs.x);
        float mpy = fminf(nyl * cs.y, nyh * cs.y);
        float minP = mpx + mpy + 513.5f;
        int base = (int)floorf(minP) - 1;
        base = min(max(base, 0), 1027 - WIN);
        base &= ~1;                 // 16B-align window for float4 staging
        baseL[t] = base;
    }
    __syncthreads();

    int li = t & 63;
    int ai = min(li, GANG - 1);         // clamp so cst/baseL reads stay in-table

    for (int g0 = 0; g0 < AA; g0 += GANG) {
        // --- coalesced staging: 45 angles x 24 float4 (48 float2) ---
        for (int idx = t; idx < GANG * (WIN/2); idx += 256) {
            int al = idx / (WIN/2);
            int w  = idx - (WIN/2) * al;
            const float4* rp4 = (const float4*)(slab + (size_t)(g0 + al) * RSP + baseL[g0 + al]);
            winbuf[idx] = rp4[w];
        }
        // lane-spread per-angle constants: lane li holds angle (g0+li)'s values.
        // cst from GLOBAL (L1-hit, off the LDS pipe); bf recomputed from baseL
        // (int -> identical bits to the old angf4.w).
        float4 cv4 = cst[g0 + ai];                       // VMEM
        float bfl  = 513.5f - (float)baseL[g0 + ai];     // one b32, stride-1
        __syncthreads();

        // --- compute 45 angles: 4 scattered b64 gathers from LDS, consts via readlane ---
        if (interior) {
            #pragma unroll 5
            for (int g = 0; g < GANG; ++g) {
                float cx = rdlane_f(cv4.x, g);
                float cy = rdlane_f(cv4.y, g);
                float dz = rdlane_f(cv4.z, g);
                float bf = rdlane_f(bfl,   g);
                float P0 = fmaf(ux, cx, fmaf(nuy, cy, bf));
                float P1 = P0 + dz;
                float P2 = fmaf(2.0f, dz, P0);
                float P3 = P2 + dz;
                int j0 = (int)P0, j1 = (int)P1, j2 = (int)P2, j3 = (int)P3;
                const float2* wg = win + g * WIN;
                float2 d0 = wg[j0];
                float2 d1 = wg[j1];
                float2 d2 = wg[j2];
                float2 d3 = wg[j3];
                float f0 = fractf_(P0), f1 = fractf_(P1), f2v = fractf_(P2), f3 = fractf_(P3);
                a0 = fmaf(f0, d0.y, a0 + d0.x);
                a1 = fmaf(f1, d1.y, a1 + d1.x);
                a2 = fmaf(f2v, d2.y, a2 + d2.x);
                a3 = fmaf(f3, d3.y, a3 + d3.x);
            }
        } else {
            #pragma unroll 5
            for (int g = 0; g < GANG; ++g) {
                float cx = rdlane_f(cv4.x, g);
                float cy = rdlane_f(cv4.y, g);
                float dz = rdlane_f(cv4.z, g);
                float bf = rdlane_f(bfl,   g);
                float P0 = fmaf(ux, cx, fmaf(nuy, cy, bf));
                float P1 = P0 + dz;
                float P2 = fmaf(2.0f, dz, P0);
                float P3 = P2 + dz;
                int j0 = (int)P0, j1 = (int)P1, j2 = (int)P2, j3 = (int)P3;
                j0 = min(max(j0, 0), WIN - 1); j1 = min(max(j1, 0), WIN - 1);
                j2 = min(max(j2, 0), WIN - 1); j3 = min(max(j3, 0), WIN - 1);
                const float2* wg = win + g * WIN;
                float2 d0 = wg[j0];
                float2 d1 = wg[j1];
                float2 d2 = wg[j2];
                float2 d3 = wg[j3];
                float f0 = fractf_(P0), f1 = fractf_(P1), f2v = fractf_(P2), f3 = fractf_(P3);
                a0 = fmaf(f0, d0.y, a0 + d0.x);
                a1 = fmaf(f1, d1.y, a1 + d1.x);
                a2 = fmaf(f2v, d2.y, a2 + d2.x);
                a3 = fmaf(f3, d3.y, a3 + d3.x);
            }
        }
        __syncthreads();   // protect winbuf before next group's staging
    }

    if (interior) {
        p0[0] = a0; p0[8 << 10] = a1; p0[16 << 10] = a2; p0[24 << 10] = a3;
    } else {
        // bit-exact circle mask per pixel (in-circle px had exact j/fract; out px masked)
        float uy1 = __fadd_rn(__fmul_rn((float)(yg + 8),  DEL), -1.0f);
        float uy2 = __fadd_rn(__fmul_rn((float)(yg + 16), DEL), -1.0f);
        float uy3 = __fadd_rn(__fmul_rn((float)(yg + 24), DEL), -1.0f);
        float xx = __fmul_rn(ux, ux);
        float r20 = __fadd_rn(xx, __fmul_rn(uy,  uy));
        float r21 = __fadd_rn(xx, __fmul_rn(uy1, uy1));
        float r22 = __fadd_rn(xx, __fmul_rn(uy2, uy2));
        float r23 = __fadd_rn(xx, __fmul_rn(uy3, uy3));
        p0[0]        = (r20 <= 1.0f) ? a0 : 0.f;
        p0[8 << 10]  = (r21 <= 1.0f) ? a1 : 0.f;
        p0[16 << 10] = (r22 <= 1.0f) ? a2 : 0.f;
        p0[24 << 10] = (r23 <= 1.0f) ? a3 : 0.f;
    }
}

// ================= fallback path (R3, proven) — used if ws too small ==========
__global__ __launch_bounds__(64) void k_filter_sc(const float* __restrict__ x,
                                                  const float* __restrict__ cg,
                                                  float* __restrict__ xaf) {
    __shared__ float xsp[3264];
    int t = threadIdx.x;
    int col = blockIdx.x;
    float acc[16];
    filter_core(x, cg, xsp, t, col, acc);

    const float SC = (float)(PI_D / 360.0);
    float* rb = xaf + (size_t)col * RS;
    if (t < 12)            ((float4*)rb)[t]              = make_float4(0.f,0.f,0.f,0.f);
    else if (t < 24)       ((float4*)rb)[268 + (t - 12)] = make_float4(0.f,0.f,0.f,0.f);
    float4* o4 = (float4*)(rb + GUARD + 16 * t);
    #pragma unroll
    for (int m4 = 0; m4 < 4; ++m4)
        o4[m4] = make_float4(acc[4*m4]*SC, acc[4*m4+1]*SC, acc[4*m4+2]*SC, acc[4*m4+3]*SC);
}

__global__ __launch_bounds__(256, 4) void k_bproj_sc(const float* __restrict__ ws,
                                                     const float* __restrict__ xaf,
                                                     float* __restrict__ out) {
    const float2* cst2 = (const float2*)(ws + OFF_CST2);
    int t = threadIdx.x;
    int tx = t & 15, ty = t >> 4;
    int bx = blockIdx.x, by = blockIdx.y, b = blockIdx.z;
    int xg = bx * 16 + tx, yg = by * 16 + ty;
    const float DEL = (float)(2.0 / 1023.0);
    float ux = __fadd_rn(__fmul_rn((float)xg, DEL), -1.0f);
    float uy = __fadd_rn(__fmul_rn((float)yg, DEL), -1.0f);

    float cx0 = __fadd_rn(__fmul_rn((float)(bx*16),      DEL), -1.0f);
    float cx1 = __fadd_rn(__fmul_rn((float)(bx*16 + 15), DEL), -1.0f);
    float cy0 = __fadd_rn(__fmul_rn((float)(by*16),      DEL), -1.0f);
    float cy1 = __fadd_rn(__fmul_rn((float)(by*16 + 15), DEL), -1.0f);
    float minax = (cx0 <= 0.f && cx1 >= 0.f) ? 0.f : fminf(fabsf(cx0), fabsf(cx1));
    float minay = (cy0 <= 0.f && cy1 >= 0.f) ? 0.f : fminf(fabsf(cy0), fabsf(cy1));
    float rmin2 = minax * minax + minay * minay;

    size_t oidx = ((size_t)b << 20) + ((size_t)yg << 10) + (size_t)xg;
    if (rmin2 > 1.000001f) { out[oidx] = 0.f; return; }

    const float* row = xaf + (size_t)b * (AA * RS);
    const float BIAS = 511.5f + (float)GUARD;
    float nuy = -uy;
    float acc = 0.f;

    #pragma unroll 4
    for (int a = 0; a < AA; ++a) {
        float2 cs = cst2[a];
        float iy = fmaf(ux, cs.x, fmaf(nuy, cs.y, BIAS));
        int j = (int)iy;
        float fy = fractf_(iy);
        float v0 = row[j];
        float v1 = row[j + 1];
        acc = fmaf(fy, v1 - v0, acc + v0);
        row += RS;
    }

    float r2 = __fadd_rn(__fmul_rn(ux, ux), __fmul_rn(uy, uy));
    out[oidx] = (r2 <= 1.0f) ? acc : 0.f;
}

extern "C" void kernel_launch(void* const* d_in, const int* in_sizes, int n_in,
                              void* d_out, int out_size, void* d_ws, size_t ws_size,
                              hipStream_t stream) {
    const float* x = (const float*)d_in[0];
    float* out = (float*)d_out;
    float* ws = (float*)d_ws;
    float* cg  = ws + OFF_CG;

    hipLaunchKernelGGL(k_tables, dim3(1), dim3(512), 0, stream, ws);

    size_t need_pair = (size_t)OFF_DATA * 4 + (size_t)NCOL * RSP * sizeof(float2);
    if (ws_size >= need_pair) {
        float2* pair = (float2*)(ws + OFF_DATA);
        hipLaunchKernelGGL(k_filter_pair, dim3(NCOL), dim3(64), 0, stream, x, cg, pair);
        hipLaunchKernelGGL(k_bproj_lds, dim3(16384), dim3(256), 0, stream, ws, pair, out);
    } else {
        float* xaf = ws + OFF_DATA;
        hipLaunchKernelGGL(k_filter_sc, dim3(NCOL), dim3(64), 0, stream, x, cg, xaf);
        hipLaunchKernelGGL(k_bproj_sc, dim3(64, 64, BB), dim3(256), 0, stream, ws, xaf, out);
    }
}

// Round 4
// 617.163 us; speedup vs baseline: 1.3629x; 1.2324x over previous
//
#include <hip/hip_runtime.h>
#include <math.h>

#define HH 1024
#define AA 180
#define BB 16
#define NCOL (BB*AA)          // 2880 (b,angle) columns
#define RSP 1028              // pair-row stride (float2 entries)
#define GUARD 48              // fallback path: zero guard floats each side
#define RS 1120               // fallback row stride
#define PI_D 3.14159265358979323846

#define GANG 90               // angles staged per group (180 = 2*90)
#define WIN 48                // window entries (float2) per angle
#define CHUNK 10              // angles per SGPR-constant chunk (90 = 9*10)

// ws float-offsets
#define OFF_CG   0            // 512 filter coeffs
#define OFF_CST  512          // float4[180]: (512c, 512s, D8=-8*DEL*512*s, 0)
#define OFF_CST2 1232         // float2[180]: (c,s) fallback table
#define OFF_DATA 1600         // pair rows (float2[NCOL*RSP]) or fallback xaf

__device__ __forceinline__ float fractf_(float x) {
#if __has_builtin(__builtin_amdgcn_fractf)
    return __builtin_amdgcn_fractf(x);   // v_fract_f32
#else
    return x - floorf(x);
#endif
}

// ---------------- tables ----------------
__global__ __launch_bounds__(512) void k_tables(float* __restrict__ ws) {
    int t = threadIdx.x;
    if (t < 512) {
        double d = 2.0 * t + 1.0;
        ws[OFF_CG + t] = (float)(-2.0 / (PI_D * PI_D * d * d));
    }
    if (t < AA) {
        float thf = (float)t * 0.017453292519943295f;  // fp32(pi/180)
        double th = (double)thf;
        double c = cos(th), s = sin(th);
        float4* cst4 = (float4*)(ws + OFF_CST);
        // D8 = d(iy)/d(k) for y-step of 8 pixels: -8*DEL*512*s = -(8192/1023)*s
        cst4[t] = make_float4((float)(512.0 * c), (float)(512.0 * s),
                              (float)(-(8192.0 / 1023.0) * s), 0.f);
        float2* cst2 = (float2*)(ws + OFF_CST2);
        cst2[t] = make_float2((float)(512.0 * c), (float)(512.0 * s));
    }
}

// ---------------- shared conv core (fused angle-interp + ramp filter) ----------------
__device__ __forceinline__ void filter_core(const float* __restrict__ x,
                                            const float* __restrict__ cg,
                                            float* xsp, int t, int col,
                                            float acc[16]) {
    int b = col / AA, a = col - b * AA;

    float4* z4 = (float4*)xsp;
    #pragma unroll
    for (int i = t; i < 816; i += 64) z4[i] = make_float4(0.f, 0.f, 0.f, 0.f);
    __syncthreads();

    float ixf = (float)a * (float)(180.0/179.0) - 0.5f;
    float fl = floorf(ixf);
    int i0 = (int)fl;
    float fx = ixf - fl;
    float w0 = (i0 >= 0)      ? (1.0f - fx) : 0.0f;
    float w1 = (i0 + 1 < AA)  ? fx          : 0.0f;
    int c0 = max(i0, 0);
    int c1 = min(i0 + 1, AA - 1);
    const float* xb = x + (size_t)b * HH * AA;
    for (int i = t; i < HH; i += 64) {
        float v = w0 * xb[i * AA + c0] + w1 * xb[i * AA + c1];
        int q = 1024 + i;
        xsp[q + (q >> 4)] = v;         // lane stride 17 -> conflict-free
    }
    __syncthreads();

    int pp = 17 * t;
    float Lw[16], Rw[16];
    #pragma unroll
    for (int m = 0; m < 16; ++m) {
        int f = 1024 + m;
        acc[m] = 0.5f * xsp[pp + f + (f >> 4)];
    }
    #pragma unroll
    for (int m = 0; m < 16; ++m) {
        int f = 1 + m;
        Lw[(m + 1) & 15] = xsp[pp + f + (f >> 4)];
        int g = 2047 + m;
        Rw[(m - 1) & 15] = xsp[pp + g + (g >> 4)];
    }

    for (int it0 = 0; it0 < 512; it0 += 8) {
        #pragma unroll
        for (int u = 0; u < 8; ++u) {
            int it = it0 + u;
            float cv = cg[511 - it];
            #pragma unroll
            for (int m = 0; m < 16; ++m) {
                acc[m] = fmaf(cv, Lw[(m + 2*u + 1) & 15] + Rw[(m - 2*u - 1) & 15], acc[m]);
            }
            int fL  = 2*it + 17;
            Lw[(2*u + 1) & 15] = xsp[pp + fL  + (fL  >> 4)];
            int fL2 = 2*it + 18;
            Lw[(2*u + 2) & 15] = xsp[pp + fL2 + (fL2 >> 4)];
            int fR  = 2045 - 2*it;
            Rw[(13 - 2*u) & 15] = xsp[pp + fR  + (fR  >> 4)];
            int fR2 = 2046 - 2*it;
            Rw[(14 - 2*u) & 15] = xsp[pp + fR2 + (fR2 >> 4)];
        }
    }
}

// ---------------- pair-output filter (SLOPE layout) ----------------
// pair[s] = (y[s-2], y[s-1]-y[s-2]) * SC, zero outside; valid s in [0,1026].
__global__ __launch_bounds__(64) void k_filter_pair(const float* __restrict__ x,
                                                    const float* __restrict__ cg,
                                                    float2* __restrict__ pair) {
    __shared__ float xsp[3264];
    int t = threadIdx.x;
    int col = blockIdx.x;
    float acc[16];
    filter_core(x, cg, xsp, t, col, acc);

    const float SC = (float)(PI_D / 360.0);
    float yv[16];
    #pragma unroll
    for (int m = 0; m < 16; ++m) yv[m] = acc[m] * SC;
    float ynext = __shfl_down(yv[0], 1);
    if (t == 63) ynext = 0.f;

    float2* rowp = pair + (size_t)col * RSP;
    int s0 = 16 * t + 2;
    #pragma unroll
    for (int m = 0; m < 15; ++m) rowp[s0 + m] = make_float2(yv[m], yv[m + 1] - yv[m]);
    rowp[s0 + 15] = make_float2(yv[15], ynext - yv[15]);
    if (t == 0) {
        rowp[0] = make_float2(0.f, 0.f);
        rowp[1] = make_float2(0.f, yv[0]);     // (v=0, dv=y0-0)
    }
    if (t == 63) rowp[1026] = make_float2(0.f, 0.f);
}

// ---------------- backprojection group compute ----------------
// Constants (512c,512s,D8) come from chunked UNIFORM loads of the global cst
// table -> batched s_load_dwordx16 into SGPRs, ONE lgkm drain per 10 angles
// (R0 lesson: per-angle s_load drains kill pipelining; R3 lesson: readlane has
// a VALU->SGPR hazard costing ~5 cyc each). Per-tile base comes from LDS as
// int2-per-2-angles (b64 broadcast, ~2 cyc/angle vs R1's 16B angf4 ~4 cyc).
// bf = 513.5f - (float)base recomputed in VALU: BIT-IDENTICAL to R1's angf4.w.
#define ANGBODY(qq, K, BINT) { \
    float bf = 513.5f - (float)(BINT); \
    float P0 = fmaf(ux, (K).x, fmaf(nuy, (K).y, bf)); \
    float dz = (K).z; \
    float P1 = P0 + dz; \
    float P2 = fmaf(2.0f, dz, P0); \
    float P3 = P2 + dz; \
    int j0 = (int)P0, j1 = (int)P1, j2 = (int)P2, j3 = (int)P3; \
    if (CLAMP) { \
        j0 = min(max(j0, 0), WIN - 1); j1 = min(max(j1, 0), WIN - 1); \
        j2 = min(max(j2, 0), WIN - 1); j3 = min(max(j3, 0), WIN - 1); \
    } \
    const float2* wg = win + (c0 + (qq)) * WIN; \
    float2 d0 = wg[j0]; \
    float2 d1 = wg[j1]; \
    float2 d2 = wg[j2]; \
    float2 d3 = wg[j3]; \
    float f0 = fractf_(P0), f1 = fractf_(P1), f2v = fractf_(P2), f3 = fractf_(P3); \
    a0 = fmaf(f0,  d0.y, a0 + d0.x); \
    a1 = fmaf(f1,  d1.y, a1 + d1.x); \
    a2 = fmaf(f2v, d2.y, a2 + d2.x); \
    a3 = fmaf(f3,  d3.y, a3 + d3.x); }

template<bool CLAMP>
__device__ __forceinline__ void bp_group(const float4* __restrict__ cst,
                                         const int* baseL_s,
                                         const float2* win, int g0,
                                         float ux, float nuy,
                                         float& a0, float& a1, float& a2, float& a3)
{
    for (int c0 = 0; c0 < GANG; c0 += CHUNK) {
        int gb = g0 + c0;
        // uniform -> SGPR chunk (compiler batches into s_load_dwordx16)
        float4 k0 = cst[gb + 0], k1 = cst[gb + 1], k2 = cst[gb + 2],
               k3 = cst[gb + 3], k4 = cst[gb + 4], k5 = cst[gb + 5],
               k6 = cst[gb + 6], k7 = cst[gb + 7], k8 = cst[gb + 8],
               k9 = cst[gb + 9];
        // per-tile bases: b64 broadcast per 2 angles (gb even: 8B aligned)
        int2 q01 = *(const int2*)&baseL_s[gb + 0];
        int2 q23 = *(const int2*)&baseL_s[gb + 2];
        int2 q45 = *(const int2*)&baseL_s[gb + 4];
        int2 q67 = *(const int2*)&baseL_s[gb + 6];
        int2 q89 = *(const int2*)&baseL_s[gb + 8];
        ANGBODY(0, k0, q01.x) ANGBODY(1, k1, q01.y)
        ANGBODY(2, k2, q23.x) ANGBODY(3, k3, q23.y)
        ANGBODY(4, k4, q45.x) ANGBODY(5, k5, q45.y)
        ANGBODY(6, k6, q67.x) ANGBODY(7, k7, q67.y)
        ANGBODY(8, k8, q89.x) ANGBODY(9, k9, q89.y)
    }
}

// ---------------- LDS-staged backprojection (R4) ----------------
// R1 (482us) structure restored: ALL 4 gathers in LDS (R2: scattered global
// gathers cost ~23 cyc TA + latency -> regression), NO readlane (R3: SGPR-write
// hazard -> regression). Changes vs R1: per-angle constants via SGPR chunks +
// int2 base broadcasts (above), and GANG 45->90 (half the barriers/groups;
// 35.3 KB LDS still fits 4 blocks/CU).
__global__ __launch_bounds__(256, 4) void k_bproj_lds(const float* __restrict__ ws,
                                                      const float2* __restrict__ pair,
                                                      float* __restrict__ out) {
    __shared__ float4 winbuf[GANG * (WIN/2)];       // 34560 B
    __shared__ alignas(16) int baseL[AA];           // all 180 window bases

    const float4* cst = (const float4*)(ws + OFF_CST);
    int t = threadIdx.x;
    int n = blockIdx.x;
    // XCD-batch swizzle: blocks ≡ i (mod 8) handle batches {i, i+8} -> per-XCD
    // pair working set ~3 MB -> L2-resident.
    int b    = (n & 7) + 8 * ((n >> 3) & 1);
    int tile = n >> 4;                  // [0,1024)
    int bx = tile & 31;                 // x-tile (32 px)
    int by = tile >> 5;                 // y-tile (32 px)
    int tx = t & 31;
    int ty = t >> 5;                    // [0,8)
    int xg = bx * 32 + tx;
    int y0 = by * 32;
    int yg = y0 + ty;                   // pixel k at yg + 8k

    const float DEL = (float)(2.0 / 1023.0);
    // bit-exact jnp.linspace replication (mul then add, no contraction)
    float ux  = __fadd_rn(__fmul_rn((float)xg, DEL), -1.0f);
    float uy  = __fadd_rn(__fmul_rn((float)yg, DEL), -1.0f);
    float nuy = -uy;

    // tile-uniform corner coords
    float cxl = __fadd_rn(__fmul_rn((float)(bx*32),      DEL), -1.0f);
    float cxh = __fadd_rn(__fmul_rn((float)(bx*32 + 31), DEL), -1.0f);
    float cyl = __fadd_rn(__fmul_rn((float)(y0),         DEL), -1.0f);
    float cyh = __fadd_rn(__fmul_rn((float)(y0 + 31),    DEL), -1.0f);

    float minax = (cxl <= 0.f && cxh >= 0.f) ? 0.f : fminf(fabsf(cxl), fabsf(cxh));
    float minay = (cyl <= 0.f && cyh >= 0.f) ? 0.f : fminf(fabsf(cyl), fabsf(cyh));
    float rmin2 = minax * minax + minay * minay;
    float maxax = fmaxf(fabsf(cxl), fabsf(cxh));
    float maxay = fmaxf(fabsf(cyl), fabsf(cyh));
    float rmax2 = maxax * maxax + maxay * maxay;

    size_t o0 = ((size_t)b << 20) + ((size_t)yg << 10) + (size_t)xg;
    float* p0 = out + o0;

    if (rmin2 > 1.000001f) {            // tile fully outside: zeros, no barriers hit
        p0[0] = 0.f; p0[8 << 10] = 0.f; p0[16 << 10] = 0.f; p0[24 << 10] = 0.f;
        return;                          // block-uniform: no divergent-barrier hazard
    }

    bool interior = (rmax2 <= 0.9999f);
    const float2* slab = pair + (size_t)b * (AA * RSP);
    const float2* win = (const float2*)winbuf;
    float a0 = 0.f, a1 = 0.f, a2 = 0.f, a3 = 0.f;
    float nyl = -cyl, nyh = -cyh;

    // --- all-angle window bases, once (same ops/bits as R1's per-group calc) ---
    if (t < AA) {
        float4 cs = cst[t];
        float mpx = fminf(cxl * cs.x, cxh * cs.x);
        float mpy = fminf(nyl * cs.y, nyh * cs.y);
        float minP = mpx + mpy + 513.5f;
        int base = (int)floorf(minP) - 1;
        base = min(max(base, 0), 1027 - WIN);
        base &= ~1;                 // 16B-align window for float4 staging
        baseL[t] = base;
    }
    __syncthreads();

    for (int g0 = 0; g0 < AA; g0 += GANG) {
        // --- coalesced staging: 90 angles x 24 float4 (48 float2) ---
        for (int idx = t; idx < GANG * (WIN/2); idx += 256) {
            int al = idx / (WIN/2);
            int w  = idx - (WIN/2) * al;
            const float4* rp4 = (const float4*)(slab + (size_t)(g0 + al) * RSP + baseL[g0 + al]);
            winbuf[idx] = rp4[w];
        }
        __syncthreads();

        if (interior) bp_group<false>(cst, baseL, win, g0, ux, nuy, a0, a1, a2, a3);
        else          bp_group<true >(cst, baseL, win, g0, ux, nuy, a0, a1, a2, a3);
        __syncthreads();   // protect winbuf before next group's staging
    }

    if (interior) {
        p0[0] = a0; p0[8 << 10] = a1; p0[16 << 10] = a2; p0[24 << 10] = a3;
    } else {
        // bit-exact circle mask per pixel (in-circle px had exact j/fract; out px masked)
        float uy1 = __fadd_rn(__fmul_rn((float)(yg + 8),  DEL), -1.0f);
        float uy2 = __fadd_rn(__fmul_rn((float)(yg + 16), DEL), -1.0f);
        float uy3 = __fadd_rn(__fmul_rn((float)(yg + 24), DEL), -1.0f);
        float xx = __fmul_rn(ux, ux);
        float r20 = __fadd_rn(xx, __fmul_rn(uy,  uy));
        float r21 = __fadd_rn(xx, __fmul_rn(uy1, uy1));
        float r22 = __fadd_rn(xx, __fmul_rn(uy2, uy2));
        float r23 = __fadd_rn(xx, __fmul_rn(uy3, uy3));
        p0[0]        = (r20 <= 1.0f) ? a0 : 0.f;
        p0[8 << 10]  = (r21 <= 1.0f) ? a1 : 0.f;
        p0[16 << 10] = (r22 <= 1.0f) ? a2 : 0.f;
        p0[24 << 10] = (r23 <= 1.0f) ? a3 : 0.f;
    }
}

// ================= fallback path (R3, proven) — used if ws too small ==========
__global__ __launch_bounds__(64) void k_filter_sc(const float* __restrict__ x,
                                                  const float* __restrict__ cg,
                                                  float* __restrict__ xaf) {
    __shared__ float xsp[3264];
    int t = threadIdx.x;
    int col = blockIdx.x;
    float acc[16];
    filter_core(x, cg, xsp, t, col, acc);

    const float SC = (float)(PI_D / 360.0);
    float* rb = xaf + (size_t)col * RS;
    if (t < 12)            ((float4*)rb)[t]              = make_float4(0.f,0.f,0.f,0.f);
    else if (t < 24)       ((float4*)rb)[268 + (t - 12)] = make_float4(0.f,0.f,0.f,0.f);
    float4* o4 = (float4*)(rb + GUARD + 16 * t);
    #pragma unroll
    for (int m4 = 0; m4 < 4; ++m4)
        o4[m4] = make_float4(acc[4*m4]*SC, acc[4*m4+1]*SC, acc[4*m4+2]*SC, acc[4*m4+3]*SC);
}

__global__ __launch_bounds__(256, 4) void k_bproj_sc(const float* __restrict__ ws,
                                                     const float* __restrict__ xaf,
                                                     float* __restrict__ out) {
    const float2* cst2 = (const float2*)(ws + OFF_CST2);
    int t = threadIdx.x;
    int tx = t & 15, ty = t >> 4;
    int bx = blockIdx.x, by = blockIdx.y, b = blockIdx.z;
    int xg = bx * 16 + tx, yg = by * 16 + ty;
    const float DEL = (float)(2.0 / 1023.0);
    float ux = __fadd_rn(__fmul_rn((float)xg, DEL), -1.0f);
    float uy = __fadd_rn(__fmul_rn((float)yg, DEL), -1.0f);

    float cx0 = __fadd_rn(__fmul_rn((float)(bx*16),      DEL), -1.0f);
    float cx1 = __fadd_rn(__fmul_rn((float)(bx*16 + 15), DEL), -1.0f);
    float cy0 = __fadd_rn(__fmul_rn((float)(by*16),      DEL), -1.0f);
    float cy1 = __fadd_rn(__fmul_rn((float)(by*16 + 15), DEL), -1.0f);
    float minax = (cx0 <= 0.f && cx1 >= 0.f) ? 0.f : fminf(fabsf(cx0), fabsf(cx1));
    float minay = (cy0 <= 0.f && cy1 >= 0.f) ? 0.f : fminf(fabsf(cy0), fabsf(cy1));
    float rmin2 = minax * minax + minay * minay;

    size_t oidx = ((size_t)b << 20) + ((size_t)yg << 10) + (size_t)xg;
    if (rmin2 > 1.000001f) { out[oidx] = 0.f; return; }

    const float* row = xaf + (size_t)b * (AA * RS);
    const float BIAS = 511.5f + (float)GUARD;
    float nuy = -uy;
    float acc = 0.f;

    #pragma unroll 4
    for (int a = 0; a < AA; ++a) {
        float2 cs = cst2[a];
        float iy = fmaf(ux, cs.x, fmaf(nuy, cs.y, BIAS));
        int j = (int)iy;
        float fy = fractf_(iy);
        float v0 = row[j];
        float v1 = row[j + 1];
        acc = fmaf(fy, v1 - v0, acc + v0);
        row += RS;
    }

    float r2 = __fadd_rn(__fmul_rn(ux, ux), __fmul_rn(uy, uy));
    out[oidx] = (r2 <= 1.0f) ? acc : 0.f;
}

extern "C" void kernel_launch(void* const* d_in, const int* in_sizes, int n_in,
                              void* d_out, int out_size, void* d_ws, size_t ws_size,
                              hipStream_t stream) {
    const float* x = (const float*)d_in[0];
    float* out = (float*)d_out;
    float* ws = (float*)d_ws;
    float* cg  = ws + OFF_CG;

    hipLaunchKernelGGL(k_tables, dim3(1), dim3(512), 0, stream, ws);

    size_t need_pair = (size_t)OFF_DATA * 4 + (size_t)NCOL * RSP * sizeof(float2);
    if (ws_size >= need_pair) {
        float2* pair = (float2*)(ws + OFF_DATA);
        hipLaunchKernelGGL(k_filter_pair, dim3(NCOL), dim3(64), 0, stream, x, cg, pair);
        hipLaunchKernelGGL(k_bproj_lds, dim3(16384), dim3(256), 0, stream, ws, pair, out);
    } else {
        float* xaf = ws + OFF_DATA;
        hipLaunchKernelGGL(k_filter_sc, dim3(NCOL), dim3(64), 0, stream, x, cg, xaf);
        hipLaunchKernelGGL(k_bproj_sc, dim3(64, 64, BB), dim3(256), 0, stream, ws, xaf, out);
    }
}